// Round 8
// baseline (711.311 us; speedup 1.0000x reference)
//
#include <hip/hip_runtime.h>

// ---------------- problem constants ----------------
constexpr int BB = 8;     // batch
constexpr int NN = 2048;  // bag dim
constexpr int DD = 512;   // feature dim
constexpr int AA = 128;   // att dim
constexpr int SM_STEPS = 10;

// ---------------- helpers ----------------
typedef __attribute__((ext_vector_type(8))) short bf16x8;
typedef __attribute__((ext_vector_type(4))) float f32x4;
typedef __attribute__((ext_vector_type(8))) unsigned short u16x8;

__device__ __forceinline__ float bf2f(unsigned short u) {
  unsigned int v = ((unsigned int)u) << 16;
  union { unsigned int i; float f; } c; c.i = v; return c.f;
}
__device__ __forceinline__ unsigned short f2bf(float f) {
  union { float f; unsigned int i; } c; c.f = f;
  unsigned int v = c.i;
  unsigned int r = (v + 0x7FFFu + ((v >> 16) & 1u)) >> 16;  // RNE
  return (unsigned short)r;
}

#define GLOBAL_AS __attribute__((address_space(1)))
#define LDS_AS __attribute__((address_space(3)))

__device__ __forceinline__ void async16(const void* g, void* l) {
  __builtin_amdgcn_global_load_lds((GLOBAL_AS const void*)g, (LDS_AS void*)l, 16, 0, 0);
}

// ---------------- P1: adj f32 -> bf16 ----------------
__global__ __launch_bounds__(256) void convert_adj_kernel(
    const float* __restrict__ adj, unsigned short* __restrict__ adjb) {
  size_t i = (size_t)blockIdx.x * blockDim.x + threadIdx.x;
  size_t total = (size_t)BB * NN * NN / 4;
  size_t stride = (size_t)gridDim.x * blockDim.x;
  for (; i < total; i += stride) {
    float4 v = ((const float4*)adj)[i];
    ushort4 o;
    o.x = f2bf(v.x); o.y = f2bf(v.y); o.z = f2bf(v.z); o.w = f2bf(v.w);
    ((ushort4*)adjb)[i] = o;
  }
}

// ---------------- P1b: W1 f32 -> bf16 ----------------
__global__ __launch_bounds__(256) void convert_w1_kernel(
    const float* __restrict__ W1, unsigned short* __restrict__ w1b) {
  int i = blockIdx.x * 256 + threadIdx.x;  // AA*DD/4 = 16384 float4s
  float4 v = ((const float4*)W1)[i];
  ushort4 o;
  o.x = f2bf(v.x); o.y = f2bf(v.y); o.z = f2bf(v.z); o.w = f2bf(v.w);
  ((ushort4*)w1b)[i] = o;
}

// ---------------- P2: X [b][n][d] f32 -> XT [b][d][n] bf16 ----------------
__global__ __launch_bounds__(256) void transpose_x_kernel(
    const float* __restrict__ X, unsigned short* __restrict__ xt) {
  __shared__ float tile[64][65];
  const int b = blockIdx.z;
  const int n0 = blockIdx.x * 64, d0 = blockIdx.y * 64;
  const int t = threadIdx.x;
  for (int i = 0; i < 16; ++i) {
    int idx = t + i * 256;
    int r = idx >> 6, c = idx & 63;
    tile[r][c] = X[(size_t)b * NN * DD + (size_t)(n0 + r) * DD + d0 + c];
  }
  __syncthreads();
  for (int i = 0; i < 16; ++i) {
    int idx = t + i * 256;
    int r = idx >> 6, c = idx & 63;  // r = d-local, c = n-local
    xt[(size_t)b * DD * NN + (size_t)(d0 + r) * NN + n0 + c] = f2bf(tile[c][r]);
  }
}

// ---------------- P3: XsT [b][d][n] bf16 -> Xs [b][n][d] bf16 ----------------
__global__ __launch_bounds__(256) void transpose_xs_kernel(
    const unsigned short* __restrict__ xst, unsigned short* __restrict__ gnorm) {
  __shared__ unsigned int tile[64][65];
  const int b = blockIdx.z;
  const int n0 = blockIdx.x * 64, d0 = blockIdx.y * 64;
  const int t = threadIdx.x;
  for (int i = 0; i < 16; ++i) {
    int idx = t + i * 256;
    int r = idx >> 6, c = idx & 63;  // r = d-local, c = n-local
    tile[r][c] = xst[(size_t)b * DD * NN + (size_t)(d0 + r) * NN + n0 + c];
  }
  __syncthreads();
  for (int i = 0; i < 16; ++i) {
    int idx = t + i * 256;
    int r = idx >> 6, c = idx & 63;  // r = n-local, c = d-local
    gnorm[(size_t)b * NN * DD + (size_t)(n0 + r) * DD + d0 + c] =
        (unsigned short)tile[c][r];
  }
}

// ---------------- Sm step: gout[d][n] = alpha * sum_j gin[d][j]*adj[n][j] + (1-alpha)*XT[d][n]
// NT GEMM, BM=128(d) x BN=256(n), BK=64, 256 thr = 4 waves (2M x 2N),
// wave-tile 64x128 (4 A-frags x 8 B-frags): 2.67 MFMA per ds_read (vs 2.0 in
// the 8-wave 64x64 layout) -> LDS-read and MFMA pipes balanced (~1.2k cyc each
// per K-tile CU-wide). Triple-buffered LDS, counted vmcnt(12), one barrier per
// K-tile, NO lgkm fences (compiler emits counted lgkmcnt and pipelines reads
// under MFMAs -- required at 1 wave/SIMD).
__global__ __launch_bounds__(256, 1) void sm_step_kernel(
    const unsigned short* __restrict__ adjb,  // [B][N][N] bf16
    const unsigned short* __restrict__ gin,   // [B][D][N] bf16
    const unsigned short* __restrict__ xt,    // [B][D][N] bf16
    unsigned short* __restrict__ gout,        // [B][D][N] bf16
    const float* __restrict__ alogit) {
  constexpr int BK = 64;
  __shared__ alignas(16) unsigned char Abuf[3][128 * BK * 2];  // 16 KB/slot
  __shared__ alignas(16) unsigned char Bbuf[3][256 * BK * 2];  // 32 KB/slot

  const int t = threadIdx.x;  // 0..255
  const int b = blockIdx.z;
  const int m0 = blockIdx.y * 128;  // d tile
  const int n0 = blockIdx.x * 256;  // n tile

  const int lane = t & 63;
  const int wave = t >> 6;   // 0..3
  const int wr = wave >> 1;  // 0..1 (M half: 64 rows)
  const int wc = wave & 1;   // 0..1 (N half: 128 cols)
  const int ln = lane & 15, kq = lane >> 4;

  // ---- staging sources (pre-swizzled 32-bit element offsets) ----
  // LDS dest for thread t, unit u is LINEAR: o = u*4096 + t*16 bytes.
  // Content at o must be logical q = o ^ (((o>>7)&7)<<4) (involution).
  const unsigned short* gA = gin + (size_t)b * DD * NN;
  const unsigned short* gB = adjb + (size_t)b * NN * NN;
  int aEl[4], bEl[8];  // element offsets into gA/gB for k0=0
  int aOff[4], bOff[8];
#pragma unroll
  for (int u = 0; u < 4; ++u) {
    int o = u * 4096 + t * 16;
    int q = o ^ (((o >> 7) & 7) << 4);
    int row = q >> 7, colb = q & 127;
    aEl[u] = (m0 + row) * NN + colb / 2;
    aOff[u] = o;
  }
#pragma unroll
  for (int u = 0; u < 8; ++u) {
    int o = u * 4096 + t * 16;
    int q = o ^ (((o >> 7) & 7) << 4);
    int row = q >> 7, colb = q & 127;
    bEl[u] = (n0 + row) * NN + colb / 2;
    bOff[u] = o;
  }

#define STAGE(tkv)                                                \
  do {                                                            \
    const int sl_ = (tkv) % 3;                                    \
    const int kk_ = (tkv)*BK;                                     \
    _Pragma("unroll") for (int u = 0; u < 4; ++u)                 \
        async16(gA + aEl[u] + kk_, &Abuf[sl_][aOff[u]]);          \
    _Pragma("unroll") for (int u = 0; u < 8; ++u)                 \
        async16(gB + bEl[u] + kk_, &Bbuf[sl_][bOff[u]]);          \
  } while (0)

  f32x4 acc[4][8];
#pragma unroll
  for (int i = 0; i < 4; ++i)
#pragma unroll
    for (int j = 0; j < 8; ++j) acc[i][j] = {0.f, 0.f, 0.f, 0.f};

  // one k-slice: 4 A + 8 B ds_read_b128 then 32 MFMA; no fences -- the
  // compiler emits counted lgkmcnt and pipelines across slices.
#define SLICE(slv, ss)                                                        \
  do {                                                                        \
    const unsigned char* Ab_ = Abuf[(slv)];                                   \
    const unsigned char* Bb_ = Bbuf[(slv)];                                   \
    bf16x8 av[4], bv[8];                                                      \
    _Pragma("unroll") for (int ii = 0; ii < 4; ++ii) {                        \
      int row_ = wr * 64 + ii * 16 + ln;                                      \
      av[ii] = *(const bf16x8*)(Ab_ +                                         \
          ((row_ * 128 + (ss)*64 + kq * 16) ^ ((row_ & 7) << 4)));            \
    }                                                                         \
    _Pragma("unroll") for (int jj = 0; jj < 8; ++jj) {                        \
      int row_ = wc * 128 + jj * 16 + ln;                                     \
      bv[jj] = *(const bf16x8*)(Bb_ +                                         \
          ((row_ * 128 + (ss)*64 + kq * 16) ^ ((row_ & 7) << 4)));            \
    }                                                                         \
    _Pragma("unroll") for (int ii = 0; ii < 4; ++ii)                          \
        _Pragma("unroll") for (int jj = 0; jj < 8; ++jj)                      \
            acc[ii][jj] = __builtin_amdgcn_mfma_f32_16x16x32_bf16(            \
                av[ii], bv[jj], acc[ii][jj], 0, 0, 0);                        \
  } while (0)

  // prologue: tiles 0 and 1 in flight (12 loads each)
  STAGE(0);
  STAGE(1);

  // main loop: 32 K-tiles. Per tile: sched_barrier(0) pins all prior MFMAs/
  // reads above the barrier (rule #18: MFMAs would otherwise sink past the
  // asm barrier and break the overwrite invariant); vmcnt(12) = tile tk's
  // loads landed (tk+1's 12 still in flight, never drained to 0); barrier;
  // stage tk+2 (slot of tk-1, whose reads all completed pre-barrier).
  for (int tk = 0; tk < 30; ++tk) {
    const int sl = tk % 3;
    __builtin_amdgcn_sched_barrier(0);
    asm volatile("s_waitcnt vmcnt(12)" ::: "memory");
    asm volatile("s_barrier" ::: "memory");
    STAGE(tk + 2);
    SLICE(sl, 0);
    SLICE(sl, 1);
  }
  __builtin_amdgcn_sched_barrier(0);
  asm volatile("s_waitcnt vmcnt(12)" ::: "memory");
  asm volatile("s_barrier" ::: "memory");
  SLICE(0, 0);  // tk=30 -> slot 0
  SLICE(0, 1);
  __builtin_amdgcn_sched_barrier(0);
  asm volatile("s_waitcnt vmcnt(0)" ::: "memory");
  asm volatile("s_barrier" ::: "memory");
  SLICE(1, 0);  // tk=31 -> slot 1
  SLICE(1, 1);

#undef SLICE
#undef STAGE

  const float al = alogit[0];
  const float alpha = 1.0f / (1.0f + expf(-al));
  const float ia = 1.0f - alpha;

  // proven scalar epilogue (C map: col=lane&15, row=(lane>>4)*4+reg)
#pragma unroll
  for (int i = 0; i < 4; ++i) {
#pragma unroll
    for (int j = 0; j < 8; ++j) {
      const int mbase = m0 + wr * 64 + i * 16 + kq * 4;
      const int nn = n0 + wc * 128 + j * 16 + ln;
#pragma unroll
      for (int r = 0; r < 4; ++r) {
        size_t idx = (size_t)b * DD * NN + (size_t)(mbase + r) * NN + nn;
        float xv = bf2f(xt[idx]);
        gout[idx] = f2bf(alpha * acc[i][j][r] + ia * xv);
      }
    }
  }
}

// ---------------- proj GEMM: f[b][n] = w2 . gelu(W1 . Xs[n] + b1) via MFMA
__global__ __launch_bounds__(256) void proj_gemm_kernel(
    const unsigned short* __restrict__ gnorm,  // [B][N][D] bf16
    const unsigned short* __restrict__ w1b,    // [A][D] bf16
    const float* __restrict__ b1,              // [A]
    const float* __restrict__ w2,              // [A]
    float* __restrict__ fbuf) {                // [B][N]
  constexpr int BK = 64;
  __shared__ alignas(16) unsigned short As[128 * BK];
  __shared__ alignas(16) unsigned short Bs[128 * BK];
  __shared__ float red[4][64];

  const int t = threadIdx.x;
  const int b = blockIdx.y;
  const int n0 = blockIdx.x * 128;

  const int lane = t & 63;
  const int wave = t >> 6;
  const int wr = wave >> 1, wc = wave & 1;
  const int ln = lane & 15, kq = lane >> 4;

  const unsigned short* gA =
      gnorm + (size_t)b * NN * DD + (size_t)(n0 + (t >> 3)) * DD + (t & 7) * 8;
  const unsigned short* gB = w1b + (size_t)(t >> 3) * DD + (t & 7) * 8;

  f32x4 acc[4][4];
#pragma unroll
  for (int i = 0; i < 4; ++i)
#pragma unroll
    for (int j = 0; j < 4; ++j) acc[i][j] = {0.f, 0.f, 0.f, 0.f};

  for (int k0 = 0; k0 < DD; k0 += BK) {
#pragma unroll
    for (int c = 0; c < 4; ++c) {
      async16(gA + (size_t)(32 * c) * DD, As + 8 * t + 2048 * c);
      async16(gB + (size_t)(32 * c) * DD, Bs + 8 * t + 2048 * c);
    }
    gA += BK;
    gB += BK;
    asm volatile("s_waitcnt vmcnt(0)" ::: "memory");
    __syncthreads();

#pragma unroll
    for (int s = 0; s < 2; ++s) {
      bf16x8 af[4], bfr[4];
#pragma unroll
      for (int i = 0; i < 4; ++i)
        af[i] = *(const bf16x8*)(&As[(wr * 64 + i * 16 + ln) * BK + s * 32 + kq * 8]);
#pragma unroll
      for (int j = 0; j < 4; ++j)
        bfr[j] = *(const bf16x8*)(&Bs[(wc * 64 + j * 16 + ln) * BK + s * 32 + kq * 8]);
#pragma unroll
      for (int i = 0; i < 4; ++i)
#pragma unroll
        for (int j = 0; j < 4; ++j)
          acc[i][j] =
              __builtin_amdgcn_mfma_f32_16x16x32_bf16(af[i], bfr[j], acc[i][j], 0, 0, 0);
    }
    __syncthreads();
  }

  float b1v[4], w2v[4];
#pragma unroll
  for (int j = 0; j < 4; ++j) {
    int a = wc * 64 + j * 16 + ln;
    b1v[j] = b1[a];
    w2v[j] = w2[a];
  }
  float p[4][4];
#pragma unroll
  for (int i = 0; i < 4; ++i)
#pragma unroll
    for (int r = 0; r < 4; ++r) {
      float s = 0.f;
#pragma unroll
      for (int j = 0; j < 4; ++j) {
        float x = acc[i][j][r] + b1v[j];
        float g = 0.5f * x * (1.0f + erff(x * 0.70710678118654752f));
        s += g * w2v[j];
      }
      p[i][r] = s;
    }
#pragma unroll
  for (int m = 1; m < 16; m <<= 1)
#pragma unroll
    for (int i = 0; i < 4; ++i)
#pragma unroll
      for (int r = 0; r < 4; ++r) p[i][r] += __shfl_xor(p[i][r], m);

  if (ln == 0) {
#pragma unroll
    for (int i = 0; i < 4; ++i)
#pragma unroll
      for (int r = 0; r < 4; ++r) red[wave][i * 16 + kq * 4 + r] = p[i][r];
  }
  __syncthreads();
  if (t < 128) {
    int w0 = (t >> 6) * 2, loc = t & 63;
    fbuf[(size_t)b * NN + n0 + t] = red[w0][loc] + red[w0 + 1][loc];
  }
}

// ---------------- K4a: masked softmax over n ----------------
__global__ __launch_bounds__(256) void softmax_kernel(
    const float* __restrict__ fbuf, const float* __restrict__ mask,
    float* __restrict__ sbuf) {
  __shared__ float red[8];
  const int b = blockIdx.x, t = threadIdx.x;
  float v[8];
  float mx = -INFINITY;
  for (int i = 0; i < 8; ++i) {
    int n = t + i * 256;
    float mk = mask[(size_t)b * NN + n];
    float lv = fbuf[(size_t)b * NN + n];
    v[i] = (mk > 0.f) ? lv : -INFINITY;
    mx = fmaxf(mx, v[i]);
  }
  for (int d = 32; d; d >>= 1) mx = fmaxf(mx, __shfl_xor(mx, d));
  if ((t & 63) == 0) red[t >> 6] = mx;
  __syncthreads();
  mx = fmaxf(fmaxf(red[0], red[1]), fmaxf(red[2], red[3]));
  float sum = 0.f;
  float e[8];
  for (int i = 0; i < 8; ++i) {
    e[i] = (v[i] == -INFINITY) ? 0.f : expf(v[i] - mx);
    sum += e[i];
  }
  for (int d = 32; d; d >>= 1) sum += __shfl_xor(sum, d);
  if ((t & 63) == 0) red[4 + (t >> 6)] = sum;
  __syncthreads();
  sum = red[4] + red[5] + red[6] + red[7];
  float inv = 1.0f / sum;
  for (int i = 0; i < 8; ++i) sbuf[(size_t)b * NN + t + i * 256] = e[i] * inv;
}

// ---------------- K4b: z[b][d] = sum_n s[b][n] * XsT[b][d][n] ----------------
__global__ __launch_bounds__(256) void pool_kernel(
    const unsigned short* __restrict__ xst, const float* __restrict__ sbuf,
    float* __restrict__ zout) {
  __shared__ float sL[NN];
  const int b = blockIdx.y, t = threadIdx.x;
  const int d0 = blockIdx.x * 8;
  for (int i = 0; i < 8; ++i) sL[t + i * 256] = sbuf[(size_t)b * NN + t + i * 256];
  __syncthreads();
  const int row = t >> 5, c = t & 31;
  const int d = d0 + row;
  const unsigned short* xr = xst + (size_t)b * DD * NN + (size_t)d * NN;
  float acc = 0.f;
  for (int i = 0; i < 8; ++i) {
    int nb = c * 64 + i * 8;
    u16x8 x = *(const u16x8*)(xr + nb);
#pragma unroll
    for (int j = 0; j < 8; ++j) acc += bf2f((unsigned short)x[j]) * sL[nb + j];
  }
  for (int dlt = 16; dlt; dlt >>= 1) acc += __shfl_xor(acc, dlt);
  if (c == 0) zout[(size_t)b * DD + d] = acc;
}

// ---------------- launch ----------------
extern "C" void kernel_launch(void* const* d_in, const int* in_sizes, int n_in,
                              void* d_out, int out_size, void* d_ws, size_t ws_size,
                              hipStream_t stream) {
  const float* X = (const float*)d_in[0];
  const float* adj = (const float*)d_in[1];
  const float* mask = (const float*)d_in[2];
  const float* W1 = (const float*)d_in[3];
  const float* b1 = (const float*)d_in[4];
  const float* w2 = (const float*)d_in[5];
  const float* alogit = (const float*)d_in[6];
  float* zout = (float*)d_out;

  char* ws = (char*)d_ws;
  unsigned short* adjb = (unsigned short*)ws;
  unsigned short* w1b = (unsigned short*)ws;  // reuse after sm steps
  unsigned short* xt = (unsigned short*)(ws + ((size_t)64 << 20));
  unsigned short* gnorm = (unsigned short*)(ws + ((size_t)64 << 20));  // reuse
  unsigned short* p0 = (unsigned short*)(ws + ((size_t)80 << 20));
  unsigned short* p1 = (unsigned short*)(ws + ((size_t)96 << 20));
  float* fbuf = (float*)(ws + ((size_t)112 << 20));
  float* sbuf = (float*)(ws + ((size_t)112 << 20) + 65536);

  hipLaunchKernelGGL(convert_adj_kernel, dim3(2048), dim3(256), 0, stream, adj, adjb);
  hipLaunchKernelGGL(transpose_x_kernel, dim3(32, 8, 8), dim3(256), 0, stream, X, xt);

  const unsigned short* gin = xt;
  unsigned short* pp[2] = {p0, p1};
  for (int s = 0; s < SM_STEPS; ++s) {
    unsigned short* go = pp[s & 1];
    hipLaunchKernelGGL(sm_step_kernel, dim3(8, 4, 8), dim3(256), 0, stream, adjb, gin,
                       xt, go, alogit);
    gin = go;
  }
  // gin == p1 (final XsT, bf16). adjb and xt regions are now dead.

  hipLaunchKernelGGL(convert_w1_kernel, dim3(64), dim3(256), 0, stream, W1, w1b);
  hipLaunchKernelGGL(transpose_xs_kernel, dim3(32, 8, 8), dim3(256), 0, stream, gin,
                     gnorm);
  hipLaunchKernelGGL(proj_gemm_kernel, dim3(16, 8), dim3(256), 0, stream, gnorm, w1b,
                     b1, w2, fbuf);
  hipLaunchKernelGGL(softmax_kernel, dim3(8), dim3(256), 0, stream, fbuf, mask, sbuf);
  hipLaunchKernelGGL(pool_kernel, dim3(64, 8), dim3(256), 0, stream, gin, sbuf, zout);
}

// Round 9
// 500.966 us; speedup vs baseline: 1.4199x; 1.4199x over previous
//
#include <hip/hip_runtime.h>

// ---------------- problem constants ----------------
constexpr int BB = 8;     // batch
constexpr int NN = 2048;  // bag dim
constexpr int DD = 512;   // feature dim
constexpr int AA = 128;   // att dim
constexpr int SM_STEPS = 10;

// ---------------- helpers ----------------
typedef __attribute__((ext_vector_type(8))) short bf16x8;
typedef __attribute__((ext_vector_type(4))) float f32x4;
typedef __attribute__((ext_vector_type(8))) unsigned short u16x8;

__device__ __forceinline__ float bf2f(unsigned short u) {
  unsigned int v = ((unsigned int)u) << 16;
  union { unsigned int i; float f; } c; c.i = v; return c.f;
}
__device__ __forceinline__ unsigned short f2bf(float f) {
  union { float f; unsigned int i; } c; c.f = f;
  unsigned int v = c.i;
  unsigned int r = (v + 0x7FFFu + ((v >> 16) & 1u)) >> 16;  // RNE
  return (unsigned short)r;
}

#define GLOBAL_AS __attribute__((address_space(1)))
#define LDS_AS __attribute__((address_space(3)))

__device__ __forceinline__ void async16(const void* g, void* l) {
  __builtin_amdgcn_global_load_lds((GLOBAL_AS const void*)g, (LDS_AS void*)l, 16, 0, 0);
}

// ---------------- P1: adj f32 -> bf16 ----------------
__global__ __launch_bounds__(256) void convert_adj_kernel(
    const float* __restrict__ adj, unsigned short* __restrict__ adjb) {
  size_t i = (size_t)blockIdx.x * blockDim.x + threadIdx.x;
  size_t total = (size_t)BB * NN * NN / 4;
  size_t stride = (size_t)gridDim.x * blockDim.x;
  for (; i < total; i += stride) {
    float4 v = ((const float4*)adj)[i];
    ushort4 o;
    o.x = f2bf(v.x); o.y = f2bf(v.y); o.z = f2bf(v.z); o.w = f2bf(v.w);
    ((ushort4*)adjb)[i] = o;
  }
}

// ---------------- P1b: W1 f32 -> bf16 ----------------
__global__ __launch_bounds__(256) void convert_w1_kernel(
    const float* __restrict__ W1, unsigned short* __restrict__ w1b) {
  int i = blockIdx.x * 256 + threadIdx.x;  // AA*DD/4 = 16384 float4s
  float4 v = ((const float4*)W1)[i];
  ushort4 o;
  o.x = f2bf(v.x); o.y = f2bf(v.y); o.z = f2bf(v.z); o.w = f2bf(v.w);
  ((ushort4*)w1b)[i] = o;
}

// ---------------- P2: X [b][n][d] f32 -> XT [b][d][n] bf16 ----------------
__global__ __launch_bounds__(256) void transpose_x_kernel(
    const float* __restrict__ X, unsigned short* __restrict__ xt) {
  __shared__ float tile[64][65];
  const int b = blockIdx.z;
  const int n0 = blockIdx.x * 64, d0 = blockIdx.y * 64;
  const int t = threadIdx.x;
  for (int i = 0; i < 16; ++i) {
    int idx = t + i * 256;
    int r = idx >> 6, c = idx & 63;
    tile[r][c] = X[(size_t)b * NN * DD + (size_t)(n0 + r) * DD + d0 + c];
  }
  __syncthreads();
  for (int i = 0; i < 16; ++i) {
    int idx = t + i * 256;
    int r = idx >> 6, c = idx & 63;  // r = d-local, c = n-local
    xt[(size_t)b * DD * NN + (size_t)(d0 + r) * NN + n0 + c] = f2bf(tile[c][r]);
  }
}

// ---------------- P3: XsT [b][d][n] bf16 -> Xs [b][n][d] bf16 ----------------
__global__ __launch_bounds__(256) void transpose_xs_kernel(
    const unsigned short* __restrict__ xst, unsigned short* __restrict__ gnorm) {
  __shared__ unsigned int tile[64][65];
  const int b = blockIdx.z;
  const int n0 = blockIdx.x * 64, d0 = blockIdx.y * 64;
  const int t = threadIdx.x;
  for (int i = 0; i < 16; ++i) {
    int idx = t + i * 256;
    int r = idx >> 6, c = idx & 63;  // r = d-local, c = n-local
    tile[r][c] = xst[(size_t)b * DD * NN + (size_t)(d0 + r) * NN + n0 + c];
  }
  __syncthreads();
  for (int i = 0; i < 16; ++i) {
    int idx = t + i * 256;
    int r = idx >> 6, c = idx & 63;  // r = n-local, c = d-local
    gnorm[(size_t)b * NN * DD + (size_t)(n0 + r) * DD + d0 + c] =
        (unsigned short)tile[c][r];
  }
}

// ---------------- Sm step: gout[d][n] = alpha * sum_j gin[d][j]*adj[n][j] + (1-alpha)*XT[d][n]
// NT GEMM, BM=128(d) x BN=256(n), BK=64, 512 thr (8 waves 2Mx4N, 64x64/wave).
// Triple-buffered LDS, counted vmcnt(6) once per K-tile, m201-style 2 phases
// per K-tile: {8 ds_read + 3 stage -> barrier -> lgkmcnt(0) -> 16 MFMA -> barrier}.
// (Verified R4 structure, 487 us total.) Epilogue: race-safe LDS-bounce
// (__syncthreads drains ds_writes, unlike R6's raw s_barrier) -> coalesced
// ushort4 xt loads + gout stores instead of 64 scalar 2B accesses/thread.
__global__ __launch_bounds__(512) void sm_step_kernel(
    const unsigned short* __restrict__ adjb,  // [B][N][N] bf16
    const unsigned short* __restrict__ gin,   // [B][D][N] bf16
    const unsigned short* __restrict__ xt,    // [B][D][N] bf16
    unsigned short* __restrict__ gout,        // [B][D][N] bf16
    const float* __restrict__ alogit) {
  constexpr int BK = 64;
  __shared__ alignas(16) unsigned char Abuf[3][128 * BK * 2];  // 16 KB/slot
  __shared__ alignas(16) unsigned char Bbuf[3][256 * BK * 2];  // 32 KB/slot

  const int t = threadIdx.x;
  const int b = blockIdx.z;
  const int m0 = blockIdx.y * 128;  // d tile
  const int n0 = blockIdx.x * 256;  // n tile

  const int lane = t & 63;
  const int wave = t >> 6;
  const int wr = wave >> 2;  // 0..1 (M)
  const int wc = wave & 3;   // 0..3 (N)
  const int ln = lane & 15, kq = lane >> 4;

  // ---- per-thread staging sources (pre-swizzled global addresses) ----
  // LDS dest for thread t, unit u is LINEAR: o = u*8192 + t*16 bytes.
  // Content placed at o must be logical position swz(o), swz(o)=o^(((o>>7)&7)<<4).
  const unsigned short* gA = gin + (size_t)b * DD * NN;
  const unsigned short* gB = adjb + (size_t)b * NN * NN;
  const unsigned short* aSrc[2];
  const unsigned short* bSrc[4];
  int aOff[2], bOff[4];
#pragma unroll
  for (int u = 0; u < 2; ++u) {
    int o = u * 8192 + t * 16;
    int q = o ^ (((o >> 7) & 7) << 4);
    int row = q >> 7, colb = q & 127;
    aSrc[u] = gA + (size_t)(m0 + row) * NN + colb / 2;
    aOff[u] = o;
  }
#pragma unroll
  for (int u = 0; u < 4; ++u) {
    int o = u * 8192 + t * 16;
    int q = o ^ (((o >> 7) & 7) << 4);
    int row = q >> 7, colb = q & 127;
    bSrc[u] = gB + (size_t)(n0 + row) * NN + colb / 2;
    bOff[u] = o;
  }

  f32x4 acc[4][4];
#pragma unroll
  for (int i = 0; i < 4; ++i)
#pragma unroll
    for (int j = 0; j < 4; ++j) acc[i][j] = {0.f, 0.f, 0.f, 0.f};

  // one k-slice phase: 8 ds_read + optional 3 stage units + barrier pair + 16 MFMA.
  // STG: 0 = none, 1 = {A0,A1,B0}, 2 = {B1,B2,B3}
  auto phase = [&](const unsigned char* Ab, const unsigned char* Bb, int ss,
                   int stg, int tnext) {
    bf16x8 av[4], bv[4];
#pragma unroll
    for (int ii = 0; ii < 4; ++ii) {
      int row = wr * 64 + ii * 16 + ln;
      int o = (row * 128 + ss * 64 + kq * 16) ^ ((row & 7) << 4);
      av[ii] = *(const bf16x8*)(Ab + o);
    }
#pragma unroll
    for (int jj = 0; jj < 4; ++jj) {
      int row = wc * 64 + jj * 16 + ln;
      int o = (row * 128 + ss * 64 + kq * 16) ^ ((row & 7) << 4);
      bv[jj] = *(const bf16x8*)(Bb + o);
    }
    if (stg == 1) {
      const int sl = tnext % 3;
      async16(aSrc[0] + tnext * BK, &Abuf[sl][aOff[0]]);
      async16(aSrc[1] + tnext * BK, &Abuf[sl][aOff[1]]);
      async16(bSrc[0] + tnext * BK, &Bbuf[sl][bOff[0]]);
    } else if (stg == 2) {
      const int sl = tnext % 3;
      async16(bSrc[1] + tnext * BK, &Bbuf[sl][bOff[1]]);
      async16(bSrc[2] + tnext * BK, &Bbuf[sl][bOff[2]]);
      async16(bSrc[3] + tnext * BK, &Bbuf[sl][bOff[3]]);
    }
    __builtin_amdgcn_s_barrier();
    asm volatile("s_waitcnt lgkmcnt(0)" ::: "memory");
    __builtin_amdgcn_sched_barrier(0);
    __builtin_amdgcn_s_setprio(1);
#pragma unroll
    for (int ii = 0; ii < 4; ++ii)
#pragma unroll
      for (int jj = 0; jj < 4; ++jj)
        acc[ii][jj] = __builtin_amdgcn_mfma_f32_16x16x32_bf16(av[ii], bv[jj],
                                                              acc[ii][jj], 0, 0, 0);
    __builtin_amdgcn_s_setprio(0);
    __builtin_amdgcn_s_barrier();
  };

  // prologue: tiles 0 and 1 in flight (issue order A0,A1,B0,B1,B2,B3 = loop order)
#pragma unroll
  for (int tv = 0; tv < 2; ++tv) {
    const int sl = tv;
    async16(aSrc[0] + tv * BK, &Abuf[sl][aOff[0]]);
    async16(aSrc[1] + tv * BK, &Abuf[sl][aOff[1]]);
    async16(bSrc[0] + tv * BK, &Bbuf[sl][bOff[0]]);
    async16(bSrc[1] + tv * BK, &Bbuf[sl][bOff[1]]);
    async16(bSrc[2] + tv * BK, &Bbuf[sl][bOff[2]]);
    async16(bSrc[3] + tv * BK, &Bbuf[sl][bOff[3]]);
  }

  // main loop: 32 K-tiles; peel last two (no staging, constant vmcnt immediates)
  for (int tk = 0; tk < 30; ++tk) {
    const int sl = tk % 3;
    const unsigned char* Ab = Abuf[sl];
    const unsigned char* Bb = Bbuf[sl];
    asm volatile("s_waitcnt vmcnt(6)" ::: "memory");  // tile tk resident; tk+1 in flight
    __builtin_amdgcn_s_barrier();
    phase(Ab, Bb, 0, 1, tk + 2);
    phase(Ab, Bb, 1, 2, tk + 2);
  }
  asm volatile("s_waitcnt vmcnt(6)" ::: "memory");
  __builtin_amdgcn_s_barrier();
  phase(Abuf[0], Bbuf[0], 0, 0, 0);  // tk=30 (slot 0)
  phase(Abuf[0], Bbuf[0], 1, 0, 0);
  asm volatile("s_waitcnt vmcnt(0)" ::: "memory");
  __builtin_amdgcn_s_barrier();
  phase(Abuf[1], Bbuf[1], 0, 0, 0);  // tk=31 (slot 1)
  phase(Abuf[1], Bbuf[1], 1, 0, 0);

  const float al = alogit[0];
  const float alpha = 1.0f / (1.0f + expf(-al));
  const float ia = 1.0f - alpha;

  // ---- epilogue: race-safe LDS bounce -> coalesced vectorized blend+store ----
  // eout = 64 x 256 f32 (64 KB) overlaying Bbuf[0..1]. Two halves (wr groups).
  // __syncthreads() (NOT raw s_barrier) before and after the ds_writes: it
  // drains lgkmcnt so the writes are visible -- this was R6's race.
  float(*eout)[256] = (float(*)[256]) & Bbuf[0][0];
#pragma unroll
  for (int hh = 0; hh < 2; ++hh) {
    __syncthreads();  // prior chunk fully consumed / K-loop LDS reads done
    if (wr == hh) {
#pragma unroll
      for (int i = 0; i < 4; ++i)
#pragma unroll
        for (int j = 0; j < 4; ++j)
#pragma unroll
          for (int r = 0; r < 4; ++r) {
            int row = i * 16 + kq * 4 + r;          // 0..63
            int col = wc * 64 + j * 16 + ln;        // 0..255
            eout[row][col] = acc[i][j][r];
          }
    }
    __syncthreads();  // ds_writes drained + visible to all waves
#pragma unroll
    for (int it = 0; it < 8; ++it) {
      int idx = t + it * 512;     // 0..4095
      int row = idx >> 6;         // 0..63
      int c4 = (idx & 63) * 4;    // 0..252
      float4 v = *(const float4*)&eout[row][c4];
      size_t g = (size_t)b * DD * NN + (size_t)(m0 + hh * 64 + row) * NN + n0 + c4;
      ushort4 xv = *(const ushort4*)(xt + g);
      ushort4 o;
      o.x = f2bf(alpha * v.x + ia * bf2f(xv.x));
      o.y = f2bf(alpha * v.y + ia * bf2f(xv.y));
      o.z = f2bf(alpha * v.z + ia * bf2f(xv.z));
      o.w = f2bf(alpha * v.w + ia * bf2f(xv.w));
      *(ushort4*)(gout + g) = o;
    }
  }
}

// ---------------- proj GEMM: f[b][n] = w2 . gelu(W1 . Xs[n] + b1) via MFMA
__global__ __launch_bounds__(256) void proj_gemm_kernel(
    const unsigned short* __restrict__ gnorm,  // [B][N][D] bf16
    const unsigned short* __restrict__ w1b,    // [A][D] bf16
    const float* __restrict__ b1,              // [A]
    const float* __restrict__ w2,              // [A]
    float* __restrict__ fbuf) {                // [B][N]
  constexpr int BK = 64;
  __shared__ alignas(16) unsigned short As[128 * BK];
  __shared__ alignas(16) unsigned short Bs[128 * BK];
  __shared__ float red[4][64];

  const int t = threadIdx.x;
  const int b = blockIdx.y;
  const int n0 = blockIdx.x * 128;

  const int lane = t & 63;
  const int wave = t >> 6;
  const int wr = wave >> 1, wc = wave & 1;
  const int ln = lane & 15, kq = lane >> 4;

  const unsigned short* gA =
      gnorm + (size_t)b * NN * DD + (size_t)(n0 + (t >> 3)) * DD + (t & 7) * 8;
  const unsigned short* gB = w1b + (size_t)(t >> 3) * DD + (t & 7) * 8;

  f32x4 acc[4][4];
#pragma unroll
  for (int i = 0; i < 4; ++i)
#pragma unroll
    for (int j = 0; j < 4; ++j) acc[i][j] = {0.f, 0.f, 0.f, 0.f};

  for (int k0 = 0; k0 < DD; k0 += BK) {
#pragma unroll
    for (int c = 0; c < 4; ++c) {
      async16(gA + (size_t)(32 * c) * DD, As + 8 * t + 2048 * c);
      async16(gB + (size_t)(32 * c) * DD, Bs + 8 * t + 2048 * c);
    }
    gA += BK;
    gB += BK;
    asm volatile("s_waitcnt vmcnt(0)" ::: "memory");
    __syncthreads();

#pragma unroll
    for (int s = 0; s < 2; ++s) {
      bf16x8 af[4], bfr[4];
#pragma unroll
      for (int i = 0; i < 4; ++i)
        af[i] = *(const bf16x8*)(&As[(wr * 64 + i * 16 + ln) * BK + s * 32 + kq * 8]);
#pragma unroll
      for (int j = 0; j < 4; ++j)
        bfr[j] = *(const bf16x8*)(&Bs[(wc * 64 + j * 16 + ln) * BK + s * 32 + kq * 8]);
#pragma unroll
      for (int i = 0; i < 4; ++i)
#pragma unroll
        for (int j = 0; j < 4; ++j)
          acc[i][j] =
              __builtin_amdgcn_mfma_f32_16x16x32_bf16(af[i], bfr[j], acc[i][j], 0, 0, 0);
    }
    __syncthreads();
  }

  float b1v[4], w2v[4];
#pragma unroll
  for (int j = 0; j < 4; ++j) {
    int a = wc * 64 + j * 16 + ln;
    b1v[j] = b1[a];
    w2v[j] = w2[a];
  }
  float p[4][4];
#pragma unroll
  for (int i = 0; i < 4; ++i)
#pragma unroll
    for (int r = 0; r < 4; ++r) {
      float s = 0.f;
#pragma unroll
      for (int j = 0; j < 4; ++j) {
        float x = acc[i][j][r] + b1v[j];
        float g = 0.5f * x * (1.0f + erff(x * 0.70710678118654752f));
        s += g * w2v[j];
      }
      p[i][r] = s;
    }
#pragma unroll
  for (int m = 1; m < 16; m <<= 1)
#pragma unroll
    for (int i = 0; i < 4; ++i)
#pragma unroll
      for (int r = 0; r < 4; ++r) p[i][r] += __shfl_xor(p[i][r], m);

  if (ln == 0) {
#pragma unroll
    for (int i = 0; i < 4; ++i)
#pragma unroll
      for (int r = 0; r < 4; ++r) red[wave][i * 16 + kq * 4 + r] = p[i][r];
  }
  __syncthreads();
  if (t < 128) {
    int w0 = (t >> 6) * 2, loc = t & 63;
    fbuf[(size_t)b * NN + n0 + t] = red[w0][loc] + red[w0 + 1][loc];
  }
}

// ---------------- K4a: masked softmax over n ----------------
__global__ __launch_bounds__(256) void softmax_kernel(
    const float* __restrict__ fbuf, const float* __restrict__ mask,
    float* __restrict__ sbuf) {
  __shared__ float red[8];
  const int b = blockIdx.x, t = threadIdx.x;
  float v[8];
  float mx = -INFINITY;
  for (int i = 0; i < 8; ++i) {
    int n = t + i * 256;
    float mk = mask[(size_t)b * NN + n];
    float lv = fbuf[(size_t)b * NN + n];
    v[i] = (mk > 0.f) ? lv : -INFINITY;
    mx = fmaxf(mx, v[i]);
  }
  for (int d = 32; d; d >>= 1) mx = fmaxf(mx, __shfl_xor(mx, d));
  if ((t & 63) == 0) red[t >> 6] = mx;
  __syncthreads();
  mx = fmaxf(fmaxf(red[0], red[1]), fmaxf(red[2], red[3]));
  float sum = 0.f;
  float e[8];
  for (int i = 0; i < 8; ++i) {
    e[i] = (v[i] == -INFINITY) ? 0.f : expf(v[i] - mx);
    sum += e[i];
  }
  for (int d = 32; d; d >>= 1) sum += __shfl_xor(sum, d);
  if ((t & 63) == 0) red[4 + (t >> 6)] = sum;
  __syncthreads();
  sum = red[4] + red[5] + red[6] + red[7];
  float inv = 1.0f / sum;
  for (int i = 0; i < 8; ++i) sbuf[(size_t)b * NN + t + i * 256] = e[i] * inv;
}

// ---------------- K4b: z[b][d] = sum_n s[b][n] * XsT[b][d][n] ----------------
__global__ __launch_bounds__(256) void pool_kernel(
    const unsigned short* __restrict__ xst, const float* __restrict__ sbuf,
    float* __restrict__ zout) {
  __shared__ float sL[NN];
  const int b = blockIdx.y, t = threadIdx.x;
  const int d0 = blockIdx.x * 8;
  for (int i = 0; i < 8; ++i) sL[t + i * 256] = sbuf[(size_t)b * NN + t + i * 256];
  __syncthreads();
  const int row = t >> 5, c = t & 31;
  const int d = d0 + row;
  const unsigned short* xr = xst + (size_t)b * DD * NN + (size_t)d * NN;
  float acc = 0.f;
  for (int i = 0; i < 8; ++i) {
    int nb = c * 64 + i * 8;
    u16x8 x = *(const u16x8*)(xr + nb);
#pragma unroll
    for (int j = 0; j < 8; ++j) acc += bf2f((unsigned short)x[j]) * sL[nb + j];
  }
  for (int dlt = 16; dlt; dlt >>= 1) acc += __shfl_xor(acc, dlt);
  if (c == 0) zout[(size_t)b * DD + d] = acc;
}

// ---------------- launch ----------------
extern "C" void kernel_launch(void* const* d_in, const int* in_sizes, int n_in,
                              void* d_out, int out_size, void* d_ws, size_t ws_size,
                              hipStream_t stream) {
  const float* X = (const float*)d_in[0];
  const float* adj = (const float*)d_in[1];
  const float* mask = (const float*)d_in[2];
  const float* W1 = (const float*)d_in[3];
  const float* b1 = (const float*)d_in[4];
  const float* w2 = (const float*)d_in[5];
  const float* alogit = (const float*)d_in[6];
  float* zout = (float*)d_out;

  char* ws = (char*)d_ws;
  unsigned short* adjb = (unsigned short*)ws;
  unsigned short* w1b = (unsigned short*)ws;  // reuse after sm steps
  unsigned short* xt = (unsigned short*)(ws + ((size_t)64 << 20));
  unsigned short* gnorm = (unsigned short*)(ws + ((size_t)64 << 20));  // reuse
  unsigned short* p0 = (unsigned short*)(ws + ((size_t)80 << 20));
  unsigned short* p1 = (unsigned short*)(ws + ((size_t)96 << 20));
  float* fbuf = (float*)(ws + ((size_t)112 << 20));
  float* sbuf = (float*)(ws + ((size_t)112 << 20) + 65536);

  hipLaunchKernelGGL(convert_adj_kernel, dim3(2048), dim3(256), 0, stream, adj, adjb);
  hipLaunchKernelGGL(transpose_x_kernel, dim3(32, 8, 8), dim3(256), 0, stream, X, xt);

  const unsigned short* gin = xt;
  unsigned short* pp[2] = {p0, p1};
  for (int s = 0; s < SM_STEPS; ++s) {
    unsigned short* go = pp[s & 1];
    hipLaunchKernelGGL(sm_step_kernel, dim3(8, 4, 8), dim3(512), 0, stream, adjb, gin,
                       xt, go, alogit);
    gin = go;
  }
  // gin == p1 (final XsT, bf16). adjb and xt regions are now dead.

  hipLaunchKernelGGL(convert_w1_kernel, dim3(64), dim3(256), 0, stream, W1, w1b);
  hipLaunchKernelGGL(transpose_xs_kernel, dim3(32, 8, 8), dim3(256), 0, stream, gin,
                     gnorm);
  hipLaunchKernelGGL(proj_gemm_kernel, dim3(16, 8), dim3(256), 0, stream, gnorm, w1b,
                     b1, w2, fbuf);
  hipLaunchKernelGGL(softmax_kernel, dim3(8), dim3(256), 0, stream, fbuf, mask, sbuf);
  hipLaunchKernelGGL(pool_kernel, dim3(64, 8), dim3(256), 0, stream, gin, sbuf, zout);
}

// Round 10
// 485.122 us; speedup vs baseline: 1.4662x; 1.0327x over previous
//
#include <hip/hip_runtime.h>

// ---------------- problem constants ----------------
constexpr int BB = 8;     // batch
constexpr int NN = 2048;  // bag dim
constexpr int DD = 512;   // feature dim
constexpr int AA = 128;   // att dim
constexpr int SM_STEPS = 10;

// ---------------- helpers ----------------
typedef __attribute__((ext_vector_type(8))) short bf16x8;
typedef __attribute__((ext_vector_type(4))) float f32x4;
typedef __attribute__((ext_vector_type(8))) unsigned short u16x8;

__device__ __forceinline__ float bf2f(unsigned short u) {
  unsigned int v = ((unsigned int)u) << 16;
  union { unsigned int i; float f; } c; c.i = v; return c.f;
}
__device__ __forceinline__ unsigned short f2bf(float f) {
  union { float f; unsigned int i; } c; c.f = f;
  unsigned int v = c.i;
  unsigned int r = (v + 0x7FFFu + ((v >> 16) & 1u)) >> 16;  // RNE
  return (unsigned short)r;
}

#define GLOBAL_AS __attribute__((address_space(1)))
#define LDS_AS __attribute__((address_space(3)))

__device__ __forceinline__ void async16(const void* g, void* l) {
  __builtin_amdgcn_global_load_lds((GLOBAL_AS const void*)g, (LDS_AS void*)l, 16, 0, 0);
}

// ---------------- P1: adj f32 -> bf16 ----------------
__global__ __launch_bounds__(256) void convert_adj_kernel(
    const float* __restrict__ adj, unsigned short* __restrict__ adjb) {
  size_t i = (size_t)blockIdx.x * blockDim.x + threadIdx.x;
  size_t total = (size_t)BB * NN * NN / 4;
  size_t stride = (size_t)gridDim.x * blockDim.x;
  for (; i < total; i += stride) {
    float4 v = ((const float4*)adj)[i];
    ushort4 o;
    o.x = f2bf(v.x); o.y = f2bf(v.y); o.z = f2bf(v.z); o.w = f2bf(v.w);
    ((ushort4*)adjb)[i] = o;
  }
}

// ---------------- P2: X [b][n][d] f32 -> XT [b][d][n] bf16 ----------------
__global__ __launch_bounds__(256) void transpose_x_kernel(
    const float* __restrict__ X, unsigned short* __restrict__ xt) {
  __shared__ float tile[64][65];
  const int b = blockIdx.z;
  const int n0 = blockIdx.x * 64, d0 = blockIdx.y * 64;
  const int t = threadIdx.x;
  for (int i = 0; i < 16; ++i) {
    int idx = t + i * 256;
    int r = idx >> 6, c = idx & 63;
    tile[r][c] = X[(size_t)b * NN * DD + (size_t)(n0 + r) * DD + d0 + c];
  }
  __syncthreads();
  for (int i = 0; i < 16; ++i) {
    int idx = t + i * 256;
    int r = idx >> 6, c = idx & 63;  // r = d-local, c = n-local
    xt[(size_t)b * DD * NN + (size_t)(d0 + r) * NN + n0 + c] = f2bf(tile[c][r]);
  }
}

// ---------------- P3: XsT [b][d][n] bf16 -> Xs [b][n][d] bf16
//                   + folded W1 f32 -> bf16 (first 64 blocks) ----------------
__global__ __launch_bounds__(256) void transpose_xs_kernel(
    const unsigned short* __restrict__ xst, unsigned short* __restrict__ gnorm,
    const float* __restrict__ W1, unsigned short* __restrict__ w1b) {
  __shared__ unsigned int tile[64][65];
  const int b = blockIdx.z;
  const int n0 = blockIdx.x * 64, d0 = blockIdx.y * 64;
  const int t = threadIdx.x;
  // fold: W1 convert (AA*DD/4 = 16384 float4s over first 64 blocks)
  const int bid = blockIdx.x + 32 * (blockIdx.y + 8 * blockIdx.z);
  if (bid < 64) {
    int i = bid * 256 + t;
    float4 v = ((const float4*)W1)[i];
    ushort4 o;
    o.x = f2bf(v.x); o.y = f2bf(v.y); o.z = f2bf(v.z); o.w = f2bf(v.w);
    ((ushort4*)w1b)[i] = o;
  }
  for (int i = 0; i < 16; ++i) {
    int idx = t + i * 256;
    int r = idx >> 6, c = idx & 63;  // r = d-local, c = n-local
    tile[r][c] = xst[(size_t)b * DD * NN + (size_t)(d0 + r) * NN + n0 + c];
  }
  __syncthreads();
  for (int i = 0; i < 16; ++i) {
    int idx = t + i * 256;
    int r = idx >> 6, c = idx & 63;  // r = n-local, c = d-local
    gnorm[(size_t)b * NN * DD + (size_t)(n0 + r) * DD + d0 + c] =
        (unsigned short)tile[c][r];
  }
}

// ---------------- Sm step: gout[d][n] = alpha * sum_j gin[d][j]*adj[n][j] + (1-alpha)*XT[d][n]
// NT GEMM, BM=128(d) x BN=256(n), BK=64, 512 thr (8 waves 2Mx4N, 64x64/wave).
// Triple-buffered LDS, counted vmcnt(6) once per K-tile, m201-style 2 phases
// per K-tile: {8 ds_read + 3 stage -> barrier -> lgkmcnt(0) -> 16 MFMA -> barrier}.
// VERIFIED R4 structure: 487 us total, sm ~40 us/step ~860 TF (structure ceiling
// for this shape; 256^2 8-phase is grid-infeasible at M=512).
__global__ __launch_bounds__(512) void sm_step_kernel(
    const unsigned short* __restrict__ adjb,  // [B][N][N] bf16
    const unsigned short* __restrict__ gin,   // [B][D][N] bf16
    const unsigned short* __restrict__ xt,    // [B][D][N] bf16
    unsigned short* __restrict__ gout,        // [B][D][N] bf16
    const float* __restrict__ alogit) {
  constexpr int BK = 64;
  __shared__ alignas(16) unsigned char Abuf[3][128 * BK * 2];  // 16 KB/slot
  __shared__ alignas(16) unsigned char Bbuf[3][256 * BK * 2];  // 32 KB/slot

  const int t = threadIdx.x;
  const int b = blockIdx.z;
  const int m0 = blockIdx.y * 128;  // d tile
  const int n0 = blockIdx.x * 256;  // n tile

  const int lane = t & 63;
  const int wave = t >> 6;
  const int wr = wave >> 2;  // 0..1 (M)
  const int wc = wave & 3;   // 0..3 (N)
  const int ln = lane & 15, kq = lane >> 4;

  // ---- per-thread staging sources (pre-swizzled global addresses) ----
  // LDS dest for thread t, unit u is LINEAR: o = u*8192 + t*16 bytes.
  // Content placed at o must be logical position swz(o), swz(o)=o^(((o>>7)&7)<<4).
  const unsigned short* gA = gin + (size_t)b * DD * NN;
  const unsigned short* gB = adjb + (size_t)b * NN * NN;
  const unsigned short* aSrc[2];
  const unsigned short* bSrc[4];
  int aOff[2], bOff[4];
#pragma unroll
  for (int u = 0; u < 2; ++u) {
    int o = u * 8192 + t * 16;
    int q = o ^ (((o >> 7) & 7) << 4);
    int row = q >> 7, colb = q & 127;
    aSrc[u] = gA + (size_t)(m0 + row) * NN + colb / 2;
    aOff[u] = o;
  }
#pragma unroll
  for (int u = 0; u < 4; ++u) {
    int o = u * 8192 + t * 16;
    int q = o ^ (((o >> 7) & 7) << 4);
    int row = q >> 7, colb = q & 127;
    bSrc[u] = gB + (size_t)(n0 + row) * NN + colb / 2;
    bOff[u] = o;
  }

  f32x4 acc[4][4];
#pragma unroll
  for (int i = 0; i < 4; ++i)
#pragma unroll
    for (int j = 0; j < 4; ++j) acc[i][j] = {0.f, 0.f, 0.f, 0.f};

  // one k-slice phase: 8 ds_read + optional 3 stage units + barrier pair + 16 MFMA.
  // STG: 0 = none, 1 = {A0,A1,B0}, 2 = {B1,B2,B3}
  auto phase = [&](const unsigned char* Ab, const unsigned char* Bb, int ss,
                   int stg, int tnext) {
    bf16x8 av[4], bv[4];
#pragma unroll
    for (int ii = 0; ii < 4; ++ii) {
      int row = wr * 64 + ii * 16 + ln;
      int o = (row * 128 + ss * 64 + kq * 16) ^ ((row & 7) << 4);
      av[ii] = *(const bf16x8*)(Ab + o);
    }
#pragma unroll
    for (int jj = 0; jj < 4; ++jj) {
      int row = wc * 64 + jj * 16 + ln;
      int o = (row * 128 + ss * 64 + kq * 16) ^ ((row & 7) << 4);
      bv[jj] = *(const bf16x8*)(Bb + o);
    }
    if (stg == 1) {
      const int sl = tnext % 3;
      async16(aSrc[0] + tnext * BK, &Abuf[sl][aOff[0]]);
      async16(aSrc[1] + tnext * BK, &Abuf[sl][aOff[1]]);
      async16(bSrc[0] + tnext * BK, &Bbuf[sl][bOff[0]]);
    } else if (stg == 2) {
      const int sl = tnext % 3;
      async16(bSrc[1] + tnext * BK, &Bbuf[sl][bOff[1]]);
      async16(bSrc[2] + tnext * BK, &Bbuf[sl][bOff[2]]);
      async16(bSrc[3] + tnext * BK, &Bbuf[sl][bOff[3]]);
    }
    __builtin_amdgcn_s_barrier();
    asm volatile("s_waitcnt lgkmcnt(0)" ::: "memory");
    __builtin_amdgcn_sched_barrier(0);
    __builtin_amdgcn_s_setprio(1);
#pragma unroll
    for (int ii = 0; ii < 4; ++ii)
#pragma unroll
      for (int jj = 0; jj < 4; ++jj)
        acc[ii][jj] = __builtin_amdgcn_mfma_f32_16x16x32_bf16(av[ii], bv[jj],
                                                              acc[ii][jj], 0, 0, 0);
    __builtin_amdgcn_s_setprio(0);
    __builtin_amdgcn_s_barrier();
  };

  // prologue: tiles 0 and 1 in flight (issue order A0,A1,B0,B1,B2,B3 = loop order)
#pragma unroll
  for (int tv = 0; tv < 2; ++tv) {
    const int sl = tv;
    async16(aSrc[0] + tv * BK, &Abuf[sl][aOff[0]]);
    async16(aSrc[1] + tv * BK, &Abuf[sl][aOff[1]]);
    async16(bSrc[0] + tv * BK, &Bbuf[sl][bOff[0]]);
    async16(bSrc[1] + tv * BK, &Bbuf[sl][bOff[1]]);
    async16(bSrc[2] + tv * BK, &Bbuf[sl][bOff[2]]);
    async16(bSrc[3] + tv * BK, &Bbuf[sl][bOff[3]]);
  }

  // main loop: 32 K-tiles; peel last two (no staging, constant vmcnt immediates)
  for (int tk = 0; tk < 30; ++tk) {
    const int sl = tk % 3;
    const unsigned char* Ab = Abuf[sl];
    const unsigned char* Bb = Bbuf[sl];
    asm volatile("s_waitcnt vmcnt(6)" ::: "memory");  // tile tk resident; tk+1 in flight
    __builtin_amdgcn_s_barrier();
    phase(Ab, Bb, 0, 1, tk + 2);
    phase(Ab, Bb, 1, 2, tk + 2);
  }
  asm volatile("s_waitcnt vmcnt(6)" ::: "memory");
  __builtin_amdgcn_s_barrier();
  phase(Abuf[0], Bbuf[0], 0, 0, 0);  // tk=30 (slot 0)
  phase(Abuf[0], Bbuf[0], 1, 0, 0);
  asm volatile("s_waitcnt vmcnt(0)" ::: "memory");
  __builtin_amdgcn_s_barrier();
  phase(Abuf[1], Bbuf[1], 0, 0, 0);  // tk=31 (slot 1)
  phase(Abuf[1], Bbuf[1], 1, 0, 0);

  const float al = alogit[0];
  const float alpha = 1.0f / (1.0f + expf(-al));
  const float ia = 1.0f - alpha;

  // proven scalar epilogue (C map: col=lane&15, row=(lane>>4)*4+reg)
#pragma unroll
  for (int i = 0; i < 4; ++i) {
#pragma unroll
    for (int j = 0; j < 4; ++j) {
      const int mbase = m0 + wr * 64 + i * 16 + kq * 4;
      const int nn = n0 + wc * 64 + j * 16 + ln;
#pragma unroll
      for (int r = 0; r < 4; ++r) {
        size_t idx = (size_t)b * DD * NN + (size_t)(mbase + r) * NN + nn;
        float xv = bf2f(xt[idx]);
        gout[idx] = f2bf(alpha * acc[i][j][r] + ia * xv);
      }
    }
  }
}

// ---------------- proj GEMM: f[b][n] = w2 . gelu(W1 . Xs[n] + b1) via MFMA
__global__ __launch_bounds__(256) void proj_gemm_kernel(
    const unsigned short* __restrict__ gnorm,  // [B][N][D] bf16
    const unsigned short* __restrict__ w1b,    // [A][D] bf16
    const float* __restrict__ b1,              // [A]
    const float* __restrict__ w2,              // [A]
    float* __restrict__ fbuf) {                // [B][N]
  constexpr int BK = 64;
  __shared__ alignas(16) unsigned short As[128 * BK];
  __shared__ alignas(16) unsigned short Bs[128 * BK];
  __shared__ float red[4][64];

  const int t = threadIdx.x;
  const int b = blockIdx.y;
  const int n0 = blockIdx.x * 128;

  const int lane = t & 63;
  const int wave = t >> 6;
  const int wr = wave >> 1, wc = wave & 1;
  const int ln = lane & 15, kq = lane >> 4;

  const unsigned short* gA =
      gnorm + (size_t)b * NN * DD + (size_t)(n0 + (t >> 3)) * DD + (t & 7) * 8;
  const unsigned short* gB = w1b + (size_t)(t >> 3) * DD + (t & 7) * 8;

  f32x4 acc[4][4];
#pragma unroll
  for (int i = 0; i < 4; ++i)
#pragma unroll
    for (int j = 0; j < 4; ++j) acc[i][j] = {0.f, 0.f, 0.f, 0.f};

  for (int k0 = 0; k0 < DD; k0 += BK) {
#pragma unroll
    for (int c = 0; c < 4; ++c) {
      async16(gA + (size_t)(32 * c) * DD, As + 8 * t + 2048 * c);
      async16(gB + (size_t)(32 * c) * DD, Bs + 8 * t + 2048 * c);
    }
    gA += BK;
    gB += BK;
    asm volatile("s_waitcnt vmcnt(0)" ::: "memory");
    __syncthreads();

#pragma unroll
    for (int s = 0; s < 2; ++s) {
      bf16x8 af[4], bfr[4];
#pragma unroll
      for (int i = 0; i < 4; ++i)
        af[i] = *(const bf16x8*)(&As[(wr * 64 + i * 16 + ln) * BK + s * 32 + kq * 8]);
#pragma unroll
      for (int j = 0; j < 4; ++j)
        bfr[j] = *(const bf16x8*)(&Bs[(wc * 64 + j * 16 + ln) * BK + s * 32 + kq * 8]);
#pragma unroll
      for (int i = 0; i < 4; ++i)
#pragma unroll
        for (int j = 0; j < 4; ++j)
          acc[i][j] =
              __builtin_amdgcn_mfma_f32_16x16x32_bf16(af[i], bfr[j], acc[i][j], 0, 0, 0);
    }
    __syncthreads();
  }

  float b1v[4], w2v[4];
#pragma unroll
  for (int j = 0; j < 4; ++j) {
    int a = wc * 64 + j * 16 + ln;
    b1v[j] = b1[a];
    w2v[j] = w2[a];
  }
  float p[4][4];
#pragma unroll
  for (int i = 0; i < 4; ++i)
#pragma unroll
    for (int r = 0; r < 4; ++r) {
      float s = 0.f;
#pragma unroll
      for (int j = 0; j < 4; ++j) {
        float x = acc[i][j][r] + b1v[j];
        float g = 0.5f * x * (1.0f + erff(x * 0.70710678118654752f));
        s += g * w2v[j];
      }
      p[i][r] = s;
    }
#pragma unroll
  for (int m = 1; m < 16; m <<= 1)
#pragma unroll
    for (int i = 0; i < 4; ++i)
#pragma unroll
      for (int r = 0; r < 4; ++r) p[i][r] += __shfl_xor(p[i][r], m);

  if (ln == 0) {
#pragma unroll
    for (int i = 0; i < 4; ++i)
#pragma unroll
      for (int r = 0; r < 4; ++r) red[wave][i * 16 + kq * 4 + r] = p[i][r];
  }
  __syncthreads();
  if (t < 128) {
    int w0 = (t >> 6) * 2, loc = t & 63;
    fbuf[(size_t)b * NN + n0 + t] = red[w0][loc] + red[w0 + 1][loc];
  }
}

// ---------------- K4a: masked softmax over n ----------------
__global__ __launch_bounds__(256) void softmax_kernel(
    const float* __restrict__ fbuf, const float* __restrict__ mask,
    float* __restrict__ sbuf) {
  __shared__ float red[8];
  const int b = blockIdx.x, t = threadIdx.x;
  float v[8];
  float mx = -INFINITY;
  for (int i = 0; i < 8; ++i) {
    int n = t + i * 256;
    float mk = mask[(size_t)b * NN + n];
    float lv = fbuf[(size_t)b * NN + n];
    v[i] = (mk > 0.f) ? lv : -INFINITY;
    mx = fmaxf(mx, v[i]);
  }
  for (int d = 32; d; d >>= 1) mx = fmaxf(mx, __shfl_xor(mx, d));
  if ((t & 63) == 0) red[t >> 6] = mx;
  __syncthreads();
  mx = fmaxf(fmaxf(red[0], red[1]), fmaxf(red[2], red[3]));
  float sum = 0.f;
  float e[8];
  for (int i = 0; i < 8; ++i) {
    e[i] = (v[i] == -INFINITY) ? 0.f : expf(v[i] - mx);
    sum += e[i];
  }
  for (int d = 32; d; d >>= 1) sum += __shfl_xor(sum, d);
  if ((t & 63) == 0) red[4 + (t >> 6)] = sum;
  __syncthreads();
  sum = red[4] + red[5] + red[6] + red[7];
  float inv = 1.0f / sum;
  for (int i = 0; i < 8; ++i) sbuf[(size_t)b * NN + t + i * 256] = e[i] * inv;
}

// ---------------- K4b: z[b][d] = sum_n s[b][n] * XsT[b][d][n] ----------------
__global__ __launch_bounds__(256) void pool_kernel(
    const unsigned short* __restrict__ xst, const float* __restrict__ sbuf,
    float* __restrict__ zout) {
  __shared__ float sL[NN];
  const int b = blockIdx.y, t = threadIdx.x;
  const int d0 = blockIdx.x * 8;
  for (int i = 0; i < 8; ++i) sL[t + i * 256] = sbuf[(size_t)b * NN + t + i * 256];
  __syncthreads();
  const int row = t >> 5, c = t & 31;
  const int d = d0 + row;
  const unsigned short* xr = xst + (size_t)b * DD * NN + (size_t)d * NN;
  float acc = 0.f;
  for (int i = 0; i < 8; ++i) {
    int nb = c * 64 + i * 8;
    u16x8 x = *(const u16x8*)(xr + nb);
#pragma unroll
    for (int j = 0; j < 8; ++j) acc += bf2f((unsigned short)x[j]) * sL[nb + j];
  }
  for (int dlt = 16; dlt; dlt >>= 1) acc += __shfl_xor(acc, dlt);
  if (c == 0) zout[(size_t)b * DD + d] = acc;
}

// ---------------- launch ----------------
extern "C" void kernel_launch(void* const* d_in, const int* in_sizes, int n_in,
                              void* d_out, int out_size, void* d_ws, size_t ws_size,
                              hipStream_t stream) {
  const float* X = (const float*)d_in[0];
  const float* adj = (const float*)d_in[1];
  const float* mask = (const float*)d_in[2];
  const float* W1 = (const float*)d_in[3];
  const float* b1 = (const float*)d_in[4];
  const float* w2 = (const float*)d_in[5];
  const float* alogit = (const float*)d_in[6];
  float* zout = (float*)d_out;

  char* ws = (char*)d_ws;
  unsigned short* adjb = (unsigned short*)ws;
  unsigned short* w1b = (unsigned short*)ws;  // reuse after sm steps
  unsigned short* xt = (unsigned short*)(ws + ((size_t)64 << 20));
  unsigned short* gnorm = (unsigned short*)(ws + ((size_t)64 << 20));  // reuse
  unsigned short* p0 = (unsigned short*)(ws + ((size_t)80 << 20));
  unsigned short* p1 = (unsigned short*)(ws + ((size_t)96 << 20));
  float* fbuf = (float*)(ws + ((size_t)112 << 20));
  float* sbuf = (float*)(ws + ((size_t)112 << 20) + 65536);

  hipLaunchKernelGGL(convert_adj_kernel, dim3(2048), dim3(256), 0, stream, adj, adjb);
  hipLaunchKernelGGL(transpose_x_kernel, dim3(32, 8, 8), dim3(256), 0, stream, X, xt);

  const unsigned short* gin = xt;
  unsigned short* pp[2] = {p0, p1};
  for (int s = 0; s < SM_STEPS; ++s) {
    unsigned short* go = pp[s & 1];
    hipLaunchKernelGGL(sm_step_kernel, dim3(8, 4, 8), dim3(512), 0, stream, adjb, gin,
                       xt, go, alogit);
    gin = go;
  }
  // gin == p1 (final XsT, bf16). adjb and xt regions are now dead.

  hipLaunchKernelGGL(transpose_xs_kernel, dim3(32, 8, 8), dim3(256), 0, stream, gin,
                     gnorm, W1, w1b);
  hipLaunchKernelGGL(proj_gemm_kernel, dim3(16, 8), dim3(256), 0, stream, gnorm, w1b,
                     b1, w2, fbuf);
  hipLaunchKernelGGL(softmax_kernel, dim3(8), dim3(256), 0, stream, fbuf, mask, sbuf);
  hipLaunchKernelGGL(pool_kernel, dim3(64, 8), dim3(256), 0, stream, gin, sbuf, zout);
}